// Round 5
// baseline (258.469 us; speedup 1.0000x reference)
//
#include <hip/hip_runtime.h>
#include <hip/hip_bf16.h>

typedef unsigned int u32;
typedef unsigned short u16;
typedef unsigned char u8;

typedef float f32x16 __attribute__((ext_vector_type(16)));
typedef short bf16x8 __attribute__((ext_vector_type(8)));

// ---- workspace layout (bytes after 64B flag header) ------------------------
// A1eff[9 off][2 mt][2 hi][32 lane][8 k] bf16 (stencil folded into W1^T) 18432B
// A1b  [2 mt][2 hi][32 lane][8 k]       bf16 (b1/16 replicated)          2048B
// WT2p [32 ch][80 k]  bf16  K-PERMUTED to match o1 register order        5120B
// WT3p [32 row][32 k] bf16  K-permuted to o2 order, M-permuted so lane
//                           (n,hh) ends with ch 8hh..8hh+7 contiguous    2048B
// B3   [16] f32                                                            64B
#define OFF_A1  0
#define OFF_A1B 18432
#define OFF_WT2 20480
#define OFF_WT3 25600
#define OFF_B3  27648
#define PREP_N  13840   // 9216 + 1024 + 2560 + 1024 + 16

// ---------------------------------------------------------------------------
// Probe (verified R1-R4): flags[0]=1 if float inputs are bf16,
// flags[1] = mask element width in bytes (1/2/4).
// ---------------------------------------------------------------------------
__global__ void probe_kernel(const u16* __restrict__ w1h,
                             const u32* __restrict__ maskw,
                             u32* __restrict__ flags) {
  __shared__ int sg, su8, sbf;
  if (threadIdx.x == 0) { sg = 0; su8 = 0; sbf = 0; }
  __syncthreads();
  int g = 0;
#pragma unroll
  for (int i = 0; i < 8; ++i) {
    u16 h = w1h[threadIdx.x * 8 + i];
    int e = (h >> 7) & 0xFF;
    if (e >= 0xC0) g++;
  }
  if (g) atomicAdd(&sg, g);
  u32 w = maskw[threadIdx.x];
  bool bytes01 = ((w & 0xFEFEFEFEu) == 0u);
  int bsum = (int)(w & 1u) + (int)((w >> 8) & 1u) +
             (int)((w >> 16) & 1u) + (int)((w >> 24) & 1u);
  if (bytes01 && bsum >= 2) atomicAdd(&su8, 1);
  if (w == 0x3F803F80u || w == 0x00003F80u) atomicAdd(&sbf, 1);
  __syncthreads();
  if (threadIdx.x == 0) {
    flags[0] = (sg == 0) ? 1u : 0u;
    flags[1] = (su8 > 0) ? 1u : ((sbf > 0) ? 2u : 4u);
  }
}

__device__ __forceinline__ float bf2f(u16 h) {
  return __uint_as_float(((u32)h) << 16);
}
__device__ __forceinline__ u16 f2bf(float f) {  // RNE (prep only)
  u32 u = __float_as_uint(f);
  return (u16)((u + 0x7FFFu + ((u >> 16) & 1u)) >> 16);
}
// hot-path pack: round-half-up + byte-perm (3 VALU ops)
__device__ __forceinline__ u32 pkbf(float a, float b) {
  u32 ua = __float_as_uint(a) + 0x8000u;
  u32 ub = __float_as_uint(b) + 0x8000u;
  return __builtin_amdgcn_perm(ub, ua, 0x07060302);  // {b.hi16, a.hi16}
}
__device__ __forceinline__ float rdv(const void* s, int i, bool bf) {
  return bf ? bf2f(((const u16*)s)[i]) : ((const float*)s)[i];
}

// ---------------------------------------------------------------------------
// Weight prep (verified R4).
// K-permutation (layers 2,3): logical k-slot = 16s + 8hh + 2q + e holds the
// channel resident in o{1,2}[4s+q] bf16-half e of a hh-half lane:
//   L2: c = 32*(s>>1) + 8*(2*(s&1)+(q>>1)) + 4*hh + 2*(q&1) + e
//   L3: c = 8*(2*s+(q>>1)) + 4*hh + 2*(q&1) + e
// M-permutation (layer 3): row r<16 holds output channel
//   cout(r) = (r&3) + 4*((r>>3)&1) + 8*((r>>2)&1)
// so lane (n,hh) regs e<8 = channel 8hh+e (contiguous 32B per lane).
// ---------------------------------------------------------------------------
__global__ void prep_weights(const void* __restrict__ w1, const void* __restrict__ b1,
                             const void* __restrict__ w2, const void* __restrict__ b2,
                             const void* __restrict__ w3, const void* __restrict__ b3,
                             const u32* __restrict__ flags, u8* __restrict__ Wb) {
  int i = blockIdx.x * 256 + threadIdx.x;
  if (i >= PREP_N) return;
  const bool bf = flags[0] != 0;
  if (i < 9216) {                       // A1eff (verified R3)
    int off = i >> 10, rem = i & 1023;
    int mt = rem >> 9, hi = (rem >> 8) & 1, l = (rem >> 3) & 31, k8 = i & 7;
    int ch = mt * 32 + l, k = hi * 8 + k8;
    int oi = off / 3, oj = off % 3;
    const float axv[3] = {1.f, 2.f, 1.f};
    const float bxv[3] = {-1.f, 0.f, 1.f};
    float ci  = (oi == 1 && oj == 1) ? 1.f : 0.f;
    float dxv = axv[oi] * bxv[oj] * 0.125f;
    float dyv = axv[oj] * bxv[oi] * 0.125f;
    float v = ci  * rdv(w1, (3 * k + 0) * 64 + ch, bf)
            + dxv * rdv(w1, (3 * k + 1) * 64 + ch, bf)
            + dyv * rdv(w1, (3 * k + 2) * 64 + ch, bf);
    ((u16*)(Wb + OFF_A1))[i] = f2bf(v);
  } else if (i < 10240) {               // A1b: b1/16 in every k slot
    int j = i - 9216;
    int mt = j >> 9, l = (j >> 3) & 31;
    ((u16*)(Wb + OFF_A1B))[j] = f2bf(rdv(b1, mt * 32 + l, bf) * 0.0625f);
  } else if (i < 12800) {               // WT2p (K-permuted)
    int j = i - 10240, n = j / 80, k = j - n * 80;
    float v;
    if (k < 64) {
      int s = k >> 4, hh = (k >> 3) & 1, q = (k & 7) >> 1, e = k & 1;
      int c = 32 * (s >> 1) + 8 * (2 * (s & 1) + (q >> 1)) + 4 * hh + 2 * (q & 1) + e;
      v = rdv(w2, c * 32 + n, bf);
    } else {
      v = (k == 64) ? rdv(b2, n, bf) : 0.0f;
    }
    ((u16*)(Wb + OFF_WT2))[j] = f2bf(v);
  } else if (i < 13824) {               // WT3p (K- and M-permuted)
    int j = i - 12800, n = j >> 5, k = j & 31;
    float v = 0.0f;
    if (n < 16) {
      int cout = (n & 3) + 4 * ((n >> 3) & 1) + 8 * ((n >> 2) & 1);
      int s = k >> 4, hh = (k >> 3) & 1, q = (k & 7) >> 1, e = k & 1;
      int cin = 8 * (2 * s + (q >> 1)) + 4 * hh + 2 * (q & 1) + e;
      v = rdv(w3, cin * 16 + cout, bf);
    }
    ((u16*)(Wb + OFF_WT3))[j] = f2bf(v);
  } else {                              // B3 f32
    int j = i - 13824;
    ((float*)(Wb + OFF_B3))[j] = rdv(b3, j, bf);
  }
}

// ---------------------------------------------------------------------------
// Main kernel
// ---------------------------------------------------------------------------
__device__ __forceinline__ float fast_tanh(float x) {
  float e = __expf(2.0f * x);
  float r = __builtin_amdgcn_rcpf(e + 1.0f);
  return fmaf(-2.0f, r, 1.0f);
}

union U4 { uint4 q; u32 u[4]; bf16x8 h; float4 f; };

__device__ __forceinline__ void wave_lds_fence() {
  __builtin_amdgcn_wave_barrier();
  __asm__ __volatile__("s_waitcnt lgkmcnt(0)" ::: "memory");
  __builtin_amdgcn_wave_barrier();
}

#define MFMA(a, b, c) __builtin_amdgcn_mfma_f32_32x32x16_bf16((a), (b), (c), 0, 0, 0)

// LDS: 4-slot ring xs[slot][258 cols][16 ch bf16] (slot = row & 3, halo cols
// 0/257 zero) + scratch[4 waves][32 px][40B] (bf16 dx, stride-40 pad).
#define XS_STRIDE 8256
#define SCR_OFF   33024
#define SCR_WAVE  1280
#define LDS_TOTAL 38144

template <bool BF16>
__device__ __forceinline__ void stage_row(const void* __restrict__ xv,
                                          u8* __restrict__ xs,
                                          int img, int row, int tid) {
  const int slot = row & 3;
  const bool valid = (row >= 0) && (row <= 255);
  if (BF16) {
    const u16* src = (const u16*)xv + ((size_t)((img << 8) + row) << 12);
#pragma unroll
    for (int s = 0; s < 2; ++s) {
      int c = s * 256 + tid;          // 16B chunk: col c>>1, half c&1
      uint4 v = make_uint4(0, 0, 0, 0);
      if (valid) v = *(const uint4*)(src + c * 8);
      *(uint4*)(xs + slot * XS_STRIDE + ((c >> 1) + 1) * 32 + (c & 1) * 16) = v;
    }
  } else {
    const float* src = (const float*)xv + ((size_t)((img << 8) + row) << 12);
#pragma unroll
    for (int k = 0; k < 4; ++k) {
      int q = k * 256 + tid;          // float4 #q: col q>>2, ch-quad q&3
      uint2 w = make_uint2(0, 0);
      if (valid) {
        float4 v = *(const float4*)(src + q * 4);
        w.x = pkbf(v.x, v.y); w.y = pkbf(v.z, v.w);
      }
      *(uint2*)(xs + slot * XS_STRIDE + ((q >> 2) + 1) * 32 + (q & 3) * 8) = w;
    }
  }
}

template <bool BF16>
__device__ __forceinline__ void nca_body(const void* __restrict__ xv,
                                         const u8* __restrict__ Wb,
                                         const void* __restrict__ maskv, int mw,
                                         void* __restrict__ outv,
                                         u8* __restrict__ xs) {
  const int tid = threadIdx.x;
  const int l   = tid & 63;
  const int wid = tid >> 6;
  const int l31 = l & 31;
  const int hi  = l >> 5;
  const int img = blockIdx.x >> 6;          // 64 blocks per image
  const int r0  = (blockIdx.x & 63) << 2;   // 4 output rows per block

  // ---- zero halo cols (0 and 257) of all 4 ring slots ---------------------
  if (tid < 8) {
    int sl = tid >> 1, side = tid & 1;
    uint4 z = make_uint4(0, 0, 0, 0);
    uint4* d = (uint4*)(xs + sl * XS_STRIDE + (side ? 257 : 0) * 32);
    d[0] = z; d[1] = z;
  }
  // ---- prologue: stage rows r0-1, r0, r0+1 --------------------------------
  stage_row<BF16>(xv, xs, img, r0 - 1, tid);
  stage_row<BF16>(xv, xs, img, r0,     tid);
  stage_row<BF16>(xv, xs, img, r0 + 1, tid);

  // ---- hoisted invariants -------------------------------------------------
  bf16x8 A1b[2];
#pragma unroll
  for (int mt = 0; mt < 2; ++mt) {
    U4 t; t.q = *(const uint4*)(Wb + OFF_A1B + ((mt * 2 + hi) * 32 + l31) * 16);
    A1b[mt] = t.h;
  }
  bf16x8 A2f[5];
#pragma unroll
  for (int s = 0; s < 5; ++s) {
    U4 t; t.q = *(const uint4*)(Wb + OFF_WT2 + l31 * 160 + s * 32 + hi * 16);
    A2f[s] = t.h;
  }
  bf16x8 A3f[2];
#pragma unroll
  for (int s = 0; s < 2; ++s) {
    U4 t; t.q = *(const uint4*)(Wb + OFF_WT3 + l31 * 64 + s * 32 + hi * 16);
    A3f[s] = t.h;
  }
  U4 ones; ones.u[0] = ones.u[1] = ones.u[2] = ones.u[3] = 0x3F803F80u;
  U4 bb;   bb.u[0] = hi ? 0u : 0x00003F80u; bb.u[1] = 0; bb.u[2] = 0; bb.u[3] = 0;
  const float* B3f = (const float*)(Wb + OFF_B3);
  const float4 b3lo  = *(const float4*)(B3f + 8 * hi);      // ch 8hi+0..3
  const float4 b3hi4 = *(const float4*)(B3f + 8 * hi + 4);  // ch 8hi+4..7
  u8* scr = xs + SCR_OFF + wid * SCR_WAVE;

  // ---- 4 output rows, ring-buffer slide -----------------------------------
  for (int it = 0; it < 4; ++it) {
    __syncthreads();                       // staged rows visible, old slot free
    const int rr = r0 + it;
    if (it < 3) stage_row<BF16>(xv, xs, img, rr + 2, tid);   // overlaps compute
    const int growpix = ((img << 8) + rr) << 8;

#pragma unroll
    for (int u = 0; u < 2; ++u) {
      const int cb = wid * 64 + u * 32;    // tile base image col

      // ---- layer 1: 2 bias MFMA + 9 shifted-offset MFMAs ------------------
      f32x16 c0 = {0,0,0,0,0,0,0,0,0,0,0,0,0,0,0,0};
      f32x16 c1 = {0,0,0,0,0,0,0,0,0,0,0,0,0,0,0,0};
      c0 = MFMA(A1b[0], ones.h, c0);
      c1 = MFMA(A1b[1], ones.h, c1);
#pragma unroll
      for (int off = 0; off < 9; ++off) {
        const int oi = off / 3, oj = off % 3;
        U4 bx; bx.q = *(const uint4*)(xs + ((rr - 1 + oi) & 3) * XS_STRIDE +
                                      (cb + l31 + oj) * 32 + hi * 16);
        U4 a0; a0.q = *(const uint4*)(Wb + OFF_A1 + (((off * 2 + 0) * 2 + hi) * 32 + l31) * 16);
        U4 a1; a1.q = *(const uint4*)(Wb + OFF_A1 + (((off * 2 + 1) * 2 + hi) * 32 + l31) * 16);
        c0 = MFMA(a0.h, bx.h, c0);
        c1 = MFMA(a1.h, bx.h, c1);
      }

      // tanh + pack: o1[mt*8+g*2+pp] = ch(32mt+8g+4hi+2pp, +1)
      u32 o1[16];
#pragma unroll
      for (int g = 0; g < 4; ++g)
#pragma unroll
        for (int pp = 0; pp < 2; ++pp) {
          o1[g * 2 + pp]     = pkbf(fast_tanh(c0[g * 4 + 2 * pp]), fast_tanh(c0[g * 4 + 2 * pp + 1]));
          o1[8 + g * 2 + pp] = pkbf(fast_tanh(c1[g * 4 + 2 * pp]), fast_tanh(c1[g * 4 + 2 * pp + 1]));
        }

      // ---- layer 2: B-frag = o1[4s..4s+3] (K-permuted weights) ------------
      f32x16 c2 = {0,0,0,0,0,0,0,0,0,0,0,0,0,0,0,0};
#pragma unroll
      for (int s = 0; s < 4; ++s) {
        U4 bfr; bfr.u[0] = o1[4*s]; bfr.u[1] = o1[4*s+1]; bfr.u[2] = o1[4*s+2]; bfr.u[3] = o1[4*s+3];
        c2 = MFMA(A2f[s], bfr.h, c2);
      }
      c2 = MFMA(A2f[4], bb.h, c2);

      u32 o2[8];
#pragma unroll
      for (int g = 0; g < 4; ++g)
#pragma unroll
        for (int pp = 0; pp < 2; ++pp)
          o2[g * 2 + pp] = pkbf(fast_tanh(c2[g * 4 + 2 * pp]), fast_tanh(c2[g * 4 + 2 * pp + 1]));

      // ---- layer 3: B-frag = o2[4s..4s+3]; lane ends with ch 8hi..8hi+7 ---
      f32x16 c3 = {0,0,0,0,0,0,0,0,0,0,0,0,0,0,0,0};
#pragma unroll
      for (int s = 0; s < 2; ++s) {
        U4 bfr; bfr.u[0] = o2[4*s]; bfr.u[1] = o2[4*s+1]; bfr.u[2] = o2[4*s+2]; bfr.u[3] = o2[4*s+3];
        c3 = MFMA(A3f[s], bfr.h, c3);
      }

      // dx + b3 -> per-wave LDS scratch as bf16 (transpose for coalescing)
      {
        float d0 = c3[0] + b3lo.x,  d1 = c3[1] + b3lo.y;
        float d2 = c3[2] + b3lo.z,  d3 = c3[3] + b3lo.w;
        float d4 = c3[4] + b3hi4.x, d5 = c3[5] + b3hi4.y;
        float d6 = c3[6] + b3hi4.z, d7 = c3[7] + b3hi4.w;
        u8* sa = scr + l31 * 40 + hi * 16;
        *(uint2*)(sa)     = make_uint2(pkbf(d0, d1), pkbf(d2, d3));
        *(uint2*)(sa + 8) = make_uint2(pkbf(d4, d5), pkbf(d6, d7));
      }
      wave_lds_fence();

      // ---- epilogue for this 32-px tile: coalesced x reads + out writes ---
#pragma unroll
      for (int P = 0; P < 2; ++P) {
        const int px_l = P * 16 + (l >> 2);     // 0..31
        const int qd   = l & 3;                 // channel quad
        uint2 dw = *(const uint2*)(scr + px_l * 40 + qd * 8);
        float dx0 = bf2f((u16)(dw.x & 0xFFFF)), dx1 = bf2f((u16)(dw.x >> 16));
        float dx2 = bf2f((u16)(dw.y & 0xFFFF)), dx3 = bf2f((u16)(dw.y >> 16));
        const int gpx = growpix + cb + px_l;
        bool ms;
        if (mw == 1)      ms = ((const u8*)maskv)[gpx] != 0;
        else if (mw == 2) ms = ((const u16*)maskv)[gpx] != 0;
        else              ms = ((const u32*)maskv)[gpx] != 0;
        const float mf = ms ? 1.0f : 0.0f;
        const int e = gpx * 16 + qd * 4;
        if (BF16) {
          uint2 xu = *(const uint2*)((const u16*)xv + e);
          float x0 = bf2f((u16)(xu.x & 0xFFFF)), x1 = bf2f((u16)(xu.x >> 16));
          float x2 = bf2f((u16)(xu.y & 0xFFFF)), x3 = bf2f((u16)(xu.y >> 16));
          float o0 = fmaf(dx0, mf, x0), o1v = fmaf(dx1, mf, x1);
          float o2v = fmaf(dx2, mf, x2), o3v = fmaf(dx3, mf, x3);
          uint2 w; w.x = pkbf(o0, o1v); w.y = pkbf(o2v, o3v);
          *(uint2*)((u16*)outv + e) = w;
        } else {
          float4 xc = *(const float4*)((const float*)xv + e);
          float4 o;
          o.x = fmaf(dx0, mf, xc.x); o.y = fmaf(dx1, mf, xc.y);
          o.z = fmaf(dx2, mf, xc.z); o.w = fmaf(dx3, mf, xc.w);
          *(float4*)((float*)outv + e) = o;
        }
      }
      wave_lds_fence();   // reads done before next tile's scratch writes
    }
  }
}

__global__ __launch_bounds__(256, 4) void nca_main(const void* __restrict__ xv,
                                                   const u8* __restrict__ Wb,
                                                   const void* __restrict__ maskv,
                                                   const u32* __restrict__ flags,
                                                   void* __restrict__ outv) {
  __shared__ __align__(16) u8 smem[LDS_TOTAL];
  const bool isbf = flags[0] != 0;   // wave-uniform
  const int mw = (int)flags[1];
  if (isbf) nca_body<true>(xv, Wb, maskv, mw, outv, smem);
  else      nca_body<false>(xv, Wb, maskv, mw, outv, smem);
}

// ---------------------------------------------------------------------------
extern "C" void kernel_launch(void* const* d_in, const int* in_sizes, int n_in,
                              void* d_out, int out_size, void* d_ws, size_t ws_size,
                              hipStream_t stream) {
  // d_in: 0=x, 1=w1, 2=b1, 3=w2, 4=b2, 5=w3, 6=b3, 7=update_mask
  u32* flags = (u32*)d_ws;
  u8* Wb = (u8*)d_ws + 64;

  probe_kernel<<<1, 256, 0, stream>>>((const u16*)d_in[1], (const u32*)d_in[7], flags);

  prep_weights<<<(PREP_N + 255) / 256, 256, 0, stream>>>(
      d_in[1], d_in[2], d_in[3], d_in[4], d_in[5], d_in[6], flags, Wb);

  const int pixels = in_sizes[7];            // B*H*W = 1048576
  const int blocks = pixels / 1024;          // 1024: four 256-px rows per block
  nca_main<<<blocks, 256, 0, stream>>>(d_in[0], Wb, d_in[7], flags, d_out);
}